// Round 7
// baseline (24675.085 us; speedup 1.0000x reference)
//
#include <hip/hip_runtime.h>

// B=64, T=512, D=96, H=256
constexpr int Bb = 64;
constexpr int Tt = 512;
constexpr int Dd = 96;
constexpr int Hh = 256;
constexpr int BH = Bb * Hh;   // 16384 elements per h ring slot

__device__ __forceinline__ float sigf(float v) { return 1.0f / (1.0f + __expf(-v)); }

// ---- agent/LLC-scope primitives (R5's proven slow protocol) ----
__device__ __forceinline__ unsigned long long ag_ld64(const unsigned long long* p) {
    return __hip_atomic_load(p, __ATOMIC_RELAXED, __HIP_MEMORY_SCOPE_AGENT);
}
__device__ __forceinline__ void ag_ex64(unsigned long long* p, unsigned long long v) {
    __hip_atomic_exchange(p, v, __ATOMIC_RELAXED, __HIP_MEMORY_SCOPE_AGENT);
}
__device__ __forceinline__ int ag_ld32(const int* p) {
    return __hip_atomic_load(p, __ATOMIC_ACQUIRE, __HIP_MEMORY_SCOPE_AGENT);
}
__device__ __forceinline__ void ag_ex32(int* p, int v) {
    __hip_atomic_exchange(p, v, __ATOMIC_RELEASE, __HIP_MEMORY_SCOPE_AGENT);
}
// ---- XCD-local primitives ----
// workgroup-scope exchange: RMW executes at the local (XCD) L2
__device__ __forceinline__ void l2_ex64(unsigned long long* p, unsigned long long v) {
    __hip_atomic_exchange(p, v, __ATOMIC_RELAXED, __HIP_MEMORY_SCOPE_WORKGROUP);
}
__device__ __forceinline__ void l2_ex32(int* p, int v) {
    __hip_atomic_exchange(p, v, __ATOMIC_RELAXED, __HIP_MEMORY_SCOPE_WORKGROUP);
}
// sc0 load: bypass L1, served by the XCD's L2 (clean read, never dirties)
__device__ __forceinline__ unsigned long long sc0_ld64(const unsigned long long* p) {
    unsigned long long v;
    asm volatile("global_load_dwordx2 %0, %1, off sc0\n\ts_waitcnt vmcnt(0)"
                 : "=v"(v) : "v"(p) : "memory");
    return v;
}
__device__ __forceinline__ int sc0_ld32(const int* p) {
    int v;
    asm volatile("global_load_dword %0, %1, off sc0\n\ts_waitcnt vmcnt(0)"
                 : "=v"(v) : "v"(p) : "memory");
    return v;
}
__device__ __forceinline__ unsigned long long hload(bool useL2, const unsigned long long* p) {
    return useL2 ? sc0_ld64(p) : ag_ld64(p);
}

// ---------- GEMM helpers (unchanged from R5) ----------
template<int G>
__device__ __forceinline__ void load8(float* wv, const float* __restrict__ M,
                                      int ld, int kb) {
    #pragma unroll
    for (int u = 0; u < 8; ++u)
        #pragma unroll
        for (int g = 0; g < G; ++g)
            wv[u * G + g] = M[(long)(kb + u) * ld + g * Hh];
}

template<int G>
__device__ __forceinline__ void fma8(const float* wv, const float* __restrict__ sA,
                                     int kb, float4* acc) {
    #pragma unroll
    for (int u = 0; u < 8; ++u) {
        const float4 a4 = *(const float4*)(sA + (size_t)(kb + u) * 4);
        #pragma unroll
        for (int g = 0; g < G; ++g) {
            const float w = wv[u * G + g];
            acc[g].x = fmaf(w, a4.x, acc[g].x);
            acc[g].y = fmaf(w, a4.y, acc[g].y);
            acc[g].z = fmaf(w, a4.z, acc[g].z);
            acc[g].w = fmaf(w, a4.w, acc[g].w);
        }
    }
}

template<int G>
__device__ __forceinline__ void gemm_range(const float* __restrict__ M, int ld,
                                           const float* __restrict__ sA,
                                           int k0, int k1, float4* acc) {
    const int n8 = (k1 - k0) >> 3;
    float wv0[8 * G], wv1[8 * G];
    if (n8 > 0) {
        load8<G>(wv0, M, ld, k0);
        int c = 0;
        for (; c + 2 <= n8; c += 2) {
            load8<G>(wv1, M, ld, k0 + (c + 1) * 8);
            fma8<G>(wv0, sA, k0 + c * 8, acc);
            if (c + 2 < n8) load8<G>(wv0, M, ld, k0 + (c + 2) * 8);
            fma8<G>(wv1, sA, k0 + (c + 1) * 8, acc);
        }
        if (c < n8) fma8<G>(wv0, sA, k0 + c * 8, acc);
    }
    for (int k = k0 + (n8 << 3); k < k1; ++k) {
        const float4 a4 = *(const float4*)(sA + (size_t)k * 4);
        #pragma unroll
        for (int g = 0; g < G; ++g) {
            const float w = M[(long)k * ld + g * Hh];
            acc[g].x = fmaf(w, a4.x, acc[g].x);
            acc[g].y = fmaf(w, a4.y, acc[g].y);
            acc[g].z = fmaf(w, a4.z, acc[g].z);
            acc[g].w = fmaf(w, a4.w, acc[g].w);
        }
    }
}

__device__ __forceinline__ void addslot(float* sG, int slot, int lane, const float4& a) {
    atomicAdd(&sG[slot * 256 +   0 + lane], a.x);
    atomicAdd(&sG[slot * 256 +  64 + lane], a.y);
    atomicAdd(&sG[slot * 256 + 128 + lane], a.z);
    atomicAdd(&sG[slot * 256 + 192 + lane], a.w);
}

// stage 1024 tagged elements (4 rows x 256 cols), 2 per thread; watchdog degrades
__device__ __forceinline__ void stage2(bool fast, bool& deg,
                                       const unsigned long long* __restrict__ buf,
                                       int rowbase, unsigned want,
                                       float* __restrict__ sA, int koff, int tid) {
    const int i0 = tid, i1 = tid + 512;
    const int r0 = i0 & 3, k0 = i0 >> 2, r1 = i1 & 3, k1 = i1 >> 2;
    const unsigned long long* p0 = buf + (rowbase + r0) * Hh + k0;
    const unsigned long long* p1 = buf + (rowbase + r1) * Hh + k1;
    unsigned long long v0 = 0, v1 = 0;
    bool d0 = false, d1 = false;
    int wd = 0;
    do {
        const bool u2 = fast && !deg;
        if (!d0) { v0 = hload(u2, p0); d0 = ((unsigned)v0 == want); }
        if (!d1) { v1 = hload(u2, p1); d1 = ((unsigned)v1 == want); }
        if (++wd > 8192) deg = true;
    } while (!(d0 && d1));
    sA[(koff + k0) * 4 + r0] = __uint_as_float((unsigned)(v0 >> 32));
    sA[(koff + k1) * 4 + r1] = __uint_as_float((unsigned)(v1 >> 32));
}

// stage 2048 tagged elements from two buffers (layer-1: lower h(t) + own h(t-1))
__device__ __forceinline__ void stage4(bool fast, bool& deg,
                                       const unsigned long long* __restrict__ blow,
                                       unsigned wlow,
                                       const unsigned long long* __restrict__ bown,
                                       unsigned wown, int rowbase,
                                       float* __restrict__ sA, int tid) {
    const unsigned long long* p[4];
    unsigned want[4];
    int sidx[4];
    #pragma unroll
    for (int e = 0; e < 4; ++e) {
        const int i = tid + e * 512;
        const bool low = (i < 1024);
        const int ii = low ? i : i - 1024;
        const int r = ii & 3, k = ii >> 2;
        p[e]    = (low ? blow : bown) + (rowbase + r) * Hh + k;
        want[e] = low ? wlow : wown;
        sidx[e] = ((low ? 0 : 256) + k) * 4 + r;
    }
    unsigned long long v[4] = {0, 0, 0, 0};
    bool d[4] = {false, false, false, false};
    int wd = 0;
    for (;;) {
        const bool u2 = fast && !deg;
        bool all = true;
        #pragma unroll
        for (int e = 0; e < 4; ++e) {
            if (!d[e]) { v[e] = hload(u2, p[e]); d[e] = ((unsigned)v[e] == want[e]); }
            all &= d[e];
        }
        if (all) break;
        if (++wd > 8192) deg = true;
    }
    #pragma unroll
    for (int e = 0; e < 4; ++e)
        sA[sidx[e]] = __uint_as_float((unsigned)(v[e] >> 32));
}

// ws layout (bytes):
//  [0, 2MB):        4 ring units [chain*2+layer], each 4 slots x BH u64
//                   u64 = (float_bits<<32)|tag; tag of h(t)=t+1; slot=t&3
//  [2MB, +32K):     flags, 1 int per role, 128B spacing
//  [2MB+32K, +8K):  negotiation: bucket cnts, ovf, arrive x2, claimed[256], rolexcd[256]
extern "C" __global__ void __launch_bounds__(512, 2)
rnn_persist(const float* __restrict__ x, const int* __restrict__ lengths,
            const float* __restrict__ gW0, const float* __restrict__ gU0,
            const float* __restrict__ gbi0, const float* __restrict__ gbr0,
            const float* __restrict__ gW1, const float* __restrict__ gU1,
            const float* __restrict__ gbi1, const float* __restrict__ gbr1,
            const float* __restrict__ lW0, const float* __restrict__ lU0,
            const float* __restrict__ lb0,
            const float* __restrict__ lW1, const float* __restrict__ lU1,
            const float* __restrict__ lb1,
            const float* __restrict__ outW, const float* __restrict__ outb,
            float* __restrict__ out, float* __restrict__ ws)
{
    const int tid  = threadIdx.x;
    const int lane = tid & 63;
    const int wave = tid >> 6;

    char* wb = (char*)ws;
    unsigned long long* H = (unsigned long long*)wb;
    int* flags = (int*)(wb + (2 << 20));
    int* neg   = (int*)(wb + (2 << 20) + (32 << 10));

    // ---- role negotiation: claim a slot in my physical XCD's bucket ----
    // role = xcd*32 + idx (idx<32). group = role>>3 (8 members, same XCD by
    // construction). Overflow blocks take leftover roles (mixed group -> vote
    // fails naturally via rolexcd inequality -> slow protocol).
    __shared__ int sRole, sFast;
    if (tid == 0) {
        const int raw = __builtin_amdgcn_s_getreg(63508);  // hwreg(XCC_ID=20,0,32)
        const int xcd = raw & 7;
        bool distrust = (raw < 0) || (raw > 7);
        const int idx = atomicAdd(&neg[xcd * 32], 1);
        int role = -1;
        if (idx < 32) {
            role = xcd * 32 + idx;
            __hip_atomic_store(&neg[512 + role], 1, __ATOMIC_RELAXED,
                               __HIP_MEMORY_SCOPE_AGENT);
        }
        const int ovf = (role < 0) ? atomicAdd(&neg[256], 1) : 0;
        __hip_atomic_fetch_add(&neg[288], 1, __ATOMIC_ACQ_REL, __HIP_MEMORY_SCOPE_AGENT);
        while (ag_ld32(&neg[288]) < 256) __builtin_amdgcn_s_sleep(2);
        if (ag_ld32(&neg[xcd * 32]) > 40) distrust = true;   // garbage-uniform guard
        if (role < 0) {  // take the ovf-th unclaimed role (claims all visible now)
            int seen = 0;
            for (int s = 0; s < 256; ++s) {
                if (__hip_atomic_load(&neg[512 + s], __ATOMIC_RELAXED,
                                      __HIP_MEMORY_SCOPE_AGENT) == 0) {
                    if (seen == ovf) { role = s; break; }
                    ++seen;
                }
            }
        }
        __hip_atomic_store(&neg[1024 + role],
                           distrust ? (1000 + (int)blockIdx.x) : (xcd + 1),
                           __ATOMIC_RELAXED, __HIP_MEMORY_SCOPE_AGENT);
        __hip_atomic_fetch_add(&neg[320], 1, __ATOMIC_ACQ_REL, __HIP_MEMORY_SCOPE_AGENT);
        while (ag_ld32(&neg[320]) < 256) __builtin_amdgcn_s_sleep(2);
        const int g8 = role & ~7;
        const int v0 = __hip_atomic_load(&neg[1024 + g8], __ATOMIC_RELAXED,
                                         __HIP_MEMORY_SCOPE_AGENT);
        bool same = true;
        for (int i = 1; i < 8; ++i)
            same &= (__hip_atomic_load(&neg[1024 + g8 + i], __ATOMIC_RELAXED,
                                       __HIP_MEMORY_SCOPE_AGENT) == v0);
        sRole = role;
        sFast = same ? 1 : 0;
    }
    __syncthreads();
    const int role  = sRole;
    const bool fast = (sFast != 0);
    const int group = role >> 3, member = role & 7;
    // chain = XCD parity (one chain's weights per XCD L2); rg bijective per chain
    const int chain = (group >> 2) & 1;
    const int rg    = (group >> 3) * 4 + (group & 3);
    const int layer = member >> 2;
    const int jt    = member & 3;
    const int rowbase = rg * 4;
    const int cpos  = jt * 64 + lane;

    unsigned long long* own   = H + (size_t)(chain * 2 + layer) * 4 * BH;
    unsigned long long* lower = H + (size_t)(chain * 2 + 0) * 4 * BH;
    int* myflag = flags + role * 32;

    const int Ka = layer ? Hh : Dd;
    const int KA = Ka + Hh;                   // 352 or 512
    const int ld = chain ? 4 * Hh : 3 * Hh;

    const float* Wm; const float* Um;
    if (chain == 0) { Wm = layer ? gW1 : gW0; Um = layer ? gU1 : gU0; }
    else            { Wm = layer ? lW1 : lW0; Um = layer ? lU1 : lU0; }
    const float* Wp = Wm + cpos;
    const float* Up = Um + cpos - (long)Ka * ld;

    __shared__ __align__(16) float sA[512 * 4];   // A^T[k][4 rows]
    __shared__ float sG[4 * 256];

    const int r = tid >> 6, cc = tid & 63, col = jt * 64 + cc;
    int grow = 0, mylen = 0;
    float b0 = 0, b1 = 0, b2 = 0, b3 = 0, ow = 0, creg = 0.0f;
    if (tid < 256) {
        grow = rowbase + r;
        mylen = lengths[grow];
        if (chain == 0) {
            const float* bi = layer ? gbi1 : gbi0;
            const float* br = layer ? gbr1 : gbr0;
            b0 = bi[col] + br[col];
            b1 = bi[Hh + col] + br[Hh + col];
            b2 = bi[2 * Hh + col];
            b3 = br[2 * Hh + col];
        } else {
            const float* bb = layer ? lb1 : lb0;
            b0 = bb[col]; b1 = bb[Hh + col]; b2 = bb[2 * Hh + col]; b3 = bb[3 * Hh + col];
        }
        if (layer == 1) ow = outW[chain * Hh + col];
    }
    const float outb0 = outb[0];
    const int kpw = KA >> 3;
    bool deg = false;   // per-thread sticky watchdog degrade

    for (int rd = 0; rd <= Tt; ++rd) {
        const bool active = (layer == 0) ? (rd < Tt) : (rd >= 1);
        const int t = (layer == 0) ? rd : rd - 1;
        unsigned long long pubv = 0;
        unsigned long long* pubp = nullptr;

        if (active) {
            for (int i = tid; i < 4 * 256; i += 512) sG[i] = 0.0f;

            // ---- stage A^T: tagged poll is the sync ----
            if (layer == 0) {
                if (tid < 4 * Dd) {
                    const int rr2 = tid & 3, k = tid >> 2;
                    sA[k * 4 + rr2] = x[((long)(rowbase + rr2) * Tt + t) * Dd + k];
                }
                stage2(fast, deg, own + (size_t)((t - 1) & 3) * BH, rowbase,
                       (unsigned)t, sA, Dd, tid);
            } else {
                stage4(fast, deg, lower + (size_t)(t & 3) * BH, (unsigned)(t + 1),
                       own + (size_t)((t - 1) & 3) * BH, (unsigned)t,
                       rowbase, sA, tid);
            }
            __syncthreads();

            // ---- GEMM ----
            {
                const int k0 = wave * kpw, k1 = k0 + kpw;
                if (chain == 0) {
                    float4 acc[3];
                    int a = k0, b = (k1 < Ka) ? k1 : Ka;
                    if (a < b) {
                        acc[0] = acc[1] = acc[2] = float4{0, 0, 0, 0};
                        gemm_range<3>(Wp, ld, sA, a, b, acc);
                        addslot(sG, 0, lane, acc[0]);
                        addslot(sG, 1, lane, acc[1]);
                        addslot(sG, 2, lane, acc[2]);
                    }
                    a = (k0 > Ka) ? k0 : Ka; b = k1;
                    if (a < b) {
                        acc[0] = acc[1] = acc[2] = float4{0, 0, 0, 0};
                        gemm_range<3>(Up, ld, sA, a, b, acc);
                        addslot(sG, 0, lane, acc[0]);
                        addslot(sG, 1, lane, acc[1]);
                        addslot(sG, 3, lane, acc[2]);
                    }
                } else {
                    float4 acc[4];
                    int a = k0, b = (k1 < Ka) ? k1 : Ka;
                    if (a < b) {
                        acc[0] = acc[1] = acc[2] = acc[3] = float4{0, 0, 0, 0};
                        gemm_range<4>(Wp, ld, sA, a, b, acc);
                        addslot(sG, 0, lane, acc[0]); addslot(sG, 1, lane, acc[1]);
                        addslot(sG, 2, lane, acc[2]); addslot(sG, 3, lane, acc[3]);
                    }
                    a = (k0 > Ka) ? k0 : Ka; b = k1;
                    if (a < b) {
                        acc[0] = acc[1] = acc[2] = acc[3] = float4{0, 0, 0, 0};
                        gemm_range<4>(Up, ld, sA, a, b, acc);
                        addslot(sG, 0, lane, acc[0]); addslot(sG, 1, lane, acc[1]);
                        addslot(sG, 2, lane, acc[2]); addslot(sG, 3, lane, acc[3]);
                    }
                }
            }
            __syncthreads();

            // ---- L0 anti-clobber: before overwriting slot t&3 (holds h0(t-4)),
            //      ensure L1 finished round t-3 (flag >= t-2). 2 rounds slack.
            if (layer == 0 && t >= 3) {
                if (wave == 0) {
                    const int* fp = flags + ((group * 8 + 4) + (lane & 3)) * 32;
                    bool ok2 = (lane >= 4);
                    int wd = 0;
                    for (;;) {
                        if (!ok2) {
                            const bool u2 = fast && !deg;
                            const int fv = u2 ? sc0_ld32(fp) : ag_ld32(fp);
                            ok2 = (fv >= t - 2);
                        }
                        if ((__ballot(ok2) & 0xFull) == 0xFull) break;
                        if (++wd > 8192) deg = true;
                        if (!fast || deg) __builtin_amdgcn_s_sleep(1);
                    }
                }
                __syncthreads();
            }

            // ---- state update + publish ----
            if (tid < 256) {
                const float s0 = sG[tid], s1 = sG[256 + tid];
                const float s2 = sG[512 + tid], s3 = sG[768 + tid];
                const float hold = sA[(Ka + col) * 4 + r];
                const bool frozen = (t >= mylen);
                float hn;
                if (chain == 0) {
                    const float z   = sigf(s0 + b0);
                    const float rr2 = sigf(s1 + b1);
                    const float hh  = tanhf(s2 + b2 + rr2 * (s3 + b3));
                    hn = z * hold + (1.0f - z) * hh;
                    if (frozen) hn = hold;
                } else {
                    const float i_ = sigf(s0 + b0);
                    const float f_ = sigf(s1 + b1);
                    float cn = f_ * creg + i_ * tanhf(s2 + b2);
                    hn = sigf(s3 + b3) * tanhf(cn);
                    if (frozen) { hn = hold; cn = creg; }
                    creg = cn;
                }
                pubp = &own[(size_t)(t & 3) * BH + grow * Hh + col];
                pubv = ((unsigned long long)__float_as_uint(hn) << 32)
                       | (unsigned)(t + 1);
                if (fast) l2_ex64(pubp, pubv);   // local-L2 visible ~200cy
                else      ag_ex64(pubp, pubv);   // LLC (R5 slow path)
                if (layer == 1) {
                    float v = hn * ow;
                    for (int o = 32; o > 0; o >>= 1) v += __shfl_down(v, o);
                    if (cc == 0)
                        atomicAdd(&out[(long)grow * Tt + t],
                                  v + ((chain == 1 && jt == 0) ? outb0 : 0.0f));
                }
            }
        }

        // ---- flag publish + (fast) LLC backup of h (fire-and-forget) ----
        __syncthreads();
        if (tid == 0) {
            if (fast) l2_ex32(myflag, rd + 1);
            ag_ex32(myflag, rd + 1);
        }
        if (fast && pubp) ag_ex64(pubp, pubv);  // backup for degraded readers;
                                                // ack overlaps next round's stage
    }
}

extern "C" void kernel_launch(void* const* d_in, const int* in_sizes, int n_in,
                              void* d_out, int out_size, void* d_ws, size_t ws_size,
                              hipStream_t stream) {
    const float* x       = (const float*)d_in[0];
    const int*   lengths = (const int*)d_in[1];
    const float* gW0  = (const float*)d_in[2];
    const float* gU0  = (const float*)d_in[3];
    const float* gbi0 = (const float*)d_in[4];
    const float* gbr0 = (const float*)d_in[5];
    const float* gW1  = (const float*)d_in[6];
    const float* gU1  = (const float*)d_in[7];
    const float* gbi1 = (const float*)d_in[8];
    const float* gbr1 = (const float*)d_in[9];
    const float* lW0  = (const float*)d_in[10];
    const float* lU0  = (const float*)d_in[11];
    const float* lb0  = (const float*)d_in[12];
    const float* lW1  = (const float*)d_in[13];
    const float* lU1  = (const float*)d_in[14];
    const float* lb1  = (const float*)d_in[15];
    const float* outW = (const float*)d_in[16];
    const float* outb = (const float*)d_in[17];
    float* out = (float*)d_out;
    float* ws  = (float*)d_ws;

    // zero rings (2MB) + flags (32KB) + negotiation (8KB)
    hipMemsetAsync(d_ws, 0, (2 << 20) + (40 << 10), stream);
    hipMemsetAsync(d_out, 0, (size_t)out_size * sizeof(float), stream);

    rnn_persist<<<dim3(256), dim3(512), 0, stream>>>(
        x, lengths, gW0, gU0, gbi0, gbr0, gW1, gU1, gbi1, gbr1,
        lW0, lU0, lb0, lW1, lU1, lb1, outW, outb, out, ws);
}

// Round 8
// 13414.232 us; speedup vs baseline: 1.8395x; 1.8395x over previous
//
#include <hip/hip_runtime.h>

// B=64, T=512, D=96, H=256
constexpr int Tt = 512, Dd = 96, Hh = 256;
constexpr int NS  = 16;          // ring depth (slots)
constexpr int RBH = 64 * Hh;     // elements per ring slot (all 64 rows x 256 cols)

__device__ __forceinline__ float sigf(float v) { return 1.0f / (1.0f + __expf(-v)); }

// ---------- register-blocked GEMM: G gate-streams x 4 rows ----------
template<int G>
__device__ __forceinline__ void load8(float* wv, const float* __restrict__ M,
                                      int ld, int kb) {
    #pragma unroll
    for (int u = 0; u < 8; ++u)
        #pragma unroll
        for (int g = 0; g < G; ++g)
            wv[u * G + g] = M[(long)(kb + u) * ld + g * Hh];
}
template<int G>
__device__ __forceinline__ void fma8(const float* wv, const float* __restrict__ sA,
                                     int kb, float4* acc) {
    #pragma unroll
    for (int u = 0; u < 8; ++u) {
        const float4 a4 = *(const float4*)(sA + (size_t)(kb + u) * 4);  // broadcast
        #pragma unroll
        for (int g = 0; g < G; ++g) {
            const float w = wv[u * G + g];
            acc[g].x = fmaf(w, a4.x, acc[g].x);
            acc[g].y = fmaf(w, a4.y, acc[g].y);
            acc[g].z = fmaf(w, a4.z, acc[g].z);
            acc[g].w = fmaf(w, a4.w, acc[g].w);
        }
    }
}
// all segment lengths are multiples of 8 by construction
template<int G>
__device__ __forceinline__ void gemm_range(const float* __restrict__ M, int ld,
                                           const float* __restrict__ sA,
                                           int k0, int k1, float4* acc) {
    const int n8 = (k1 - k0) >> 3;
    float wv0[8 * G], wv1[8 * G];
    if (n8 <= 0) return;
    load8<G>(wv0, M, ld, k0);
    int c2 = 0;
    for (; c2 + 2 <= n8; c2 += 2) {
        load8<G>(wv1, M, ld, k0 + (c2 + 1) * 8);
        fma8<G>(wv0, sA, k0 + c2 * 8, acc);
        if (c2 + 2 < n8) load8<G>(wv0, M, ld, k0 + (c2 + 2) * 8);
        fma8<G>(wv1, sA, k0 + (c2 + 1) * 8, acc);
    }
    if (c2 < n8) fma8<G>(wv0, sA, k0 + c2 * 8, acc);
}

// ws layout (bytes):
//  [0, 4MB):      2 rings [chain] x NS slots x RBH u64 (layer0 h, tagged)
//                 u64 = (float_bits<<32) | tag; tag of h0(t) = t+1; slot = t&15
//  [4MB, +4KB):   L1 progress flags: flag[chain*16+rg] at idx*32 ints
extern "C" __global__ void __launch_bounds__(512, 1)
rnn_persist(const float* __restrict__ x, const int* __restrict__ lengths,
            const float* __restrict__ gW0, const float* __restrict__ gU0,
            const float* __restrict__ gbi0, const float* __restrict__ gbr0,
            const float* __restrict__ gW1, const float* __restrict__ gU1,
            const float* __restrict__ gbi1, const float* __restrict__ gbr1,
            const float* __restrict__ lW0, const float* __restrict__ lU0,
            const float* __restrict__ lb0,
            const float* __restrict__ lW1, const float* __restrict__ lU1,
            const float* __restrict__ lb1,
            const float* __restrict__ outW, const float* __restrict__ outb,
            float* __restrict__ out, float* __restrict__ ws)
{
    const int tid = threadIdx.x;
    const int c   = tid & 255;       // owned column (0..255)
    const int grp = tid >> 8;        // k-split group (0/1)
    const int bx  = blockIdx.x;
    // bx%8 fixes (chain, layer, rg&1) -> each XCD hosts ONE layer-type's weights
    const int chain = bx & 1;
    const int layer = (bx >> 1) & 1;
    const int rg    = ((bx >> 2) & 1) | ((bx >> 3) << 1);   // 0..15
    const int rowbase = rg * 4;

    unsigned long long* ring = (unsigned long long*)ws + (size_t)chain * NS * RBH;
    int* flags = (int*)((char*)ws + (4 << 20));
    int* myflag = &flags[(chain * 16 + rg) * 32];

    const int Ka = layer ? Hh : Dd;          // 256 or 96
    const int KA = Ka + Hh;                  // 512 or 352
    const int ld = chain ? 4 * Hh : 3 * Hh;
    // GRU: split exactly at W/U boundary (group0 = P-side, group1 = Q-side)
    // LSTM: balanced split (both multiples of 8)
    const int S  = chain ? (KA >> 1) : Ka;
    const int kg0 = grp ? S : 0, kg1 = grp ? KA : S;

    const float* Wm; const float* Um;
    if (chain == 0) { Wm = layer ? gW1 : gW0; Um = layer ? gU1 : gU0; }
    else            { Wm = layer ? lW1 : lW0; Um = layer ? lU1 : lU0; }
    const float* WpC = Wm + c;
    const float* UpC = Um + c - (long)Ka * ld;   // A-index k>=Ka addresses U row k-Ka

    __shared__ __align__(16) float sA[512 * 4];  // A^T[k][4 rows]; [Ka..KA) = own h
    __shared__ float sG[2 * 4 * 1024];           // [group][row][gatecol]
    __shared__ float sRed[16];

    // per-thread constants (column c fixed for both update elements)
    float bz = 0, b1 = 0, b2 = 0, b3 = 0;
    if (chain == 0) {
        const float* bi = layer ? gbi1 : gbi0;
        const float* br = layer ? gbr1 : gbr0;
        bz = bi[c] + br[c];
        b1 = bi[Hh + c] + br[Hh + c];
        b2 = bi[2 * Hh + c];          // bi_h (P side)
        b3 = br[2 * Hh + c];          // br_h (Q side)
    } else {
        const float* bb = layer ? lb1 : lb0;
        bz = bb[c]; b1 = bb[Hh + c]; b2 = bb[2 * Hh + c]; b3 = bb[3 * Hh + c];
    }
    const float ow = (layer == 1) ? outW[chain * Hh + c] : 0.0f;
    const float outb0 = outb[0];
    const int rA = tid >> 8;                       // update rows rA and rA+2
    const int lenA = lengths[rowbase + rA];
    const int lenB = lengths[rowbase + rA + 2];
    float creg0 = 0.0f, creg1 = 0.0f;              // LSTM c (2 elements/thread)

    // init own-h(t=-1)=0 : contiguous region sA[Ka*4 .. KA*4)
    for (int i = tid; i < 1024; i += 512) sA[Ka * 4 + i] = 0.0f;
    __syncthreads();

    for (int t = 0; t < Tt; ++t) {
        // ---- stage input part of A ----
        if (layer == 0) {
            if (tid < 4 * Dd) {
                const int r = tid / Dd, k = tid - r * Dd;
                sA[k * 4 + r] = x[((long)(rowbase + r) * Tt + t) * Dd + k];
            }
        } else {
            // poll lower h0(t) from ring slot t&15 (tag t+1); lag makes this 1 sweep
            const unsigned long long* base =
                ring + (size_t)(t & (NS - 1)) * RBH + rowbase * Hh;
            const unsigned want = (unsigned)(t + 1);
            const int r0 = tid >> 8, r1 = r0 + 2;
            const unsigned long long* p0 = base + r0 * Hh + c;
            const unsigned long long* p1 = base + r1 * Hh + c;
            unsigned long long v0 = 0, v1 = 0;
            bool d0 = false, d1 = false;
            do {
                if (!d0) { v0 = __hip_atomic_load(p0, __ATOMIC_RELAXED,
                                                  __HIP_MEMORY_SCOPE_AGENT);
                           d0 = ((unsigned)v0 == want); }
                if (!d1) { v1 = __hip_atomic_load(p1, __ATOMIC_RELAXED,
                                                  __HIP_MEMORY_SCOPE_AGENT);
                           d1 = ((unsigned)v1 == want); }
            } while (!(d0 && d1));
            sA[c * 4 + r0] = __uint_as_float((unsigned)(v0 >> 32));
            sA[c * 4 + r1] = __uint_as_float((unsigned)(v1 >> 32));
        }
        __syncthreads();
        if (layer == 1 && tid == 0)
            __hip_atomic_exchange(myflag, t + 1, __ATOMIC_RELEASE,
                                  __HIP_MEMORY_SCOPE_AGENT);   // staged h0(t)

        // ---- GEMM: this thread's column c, G gate streams, 4 rows, k in [kg0,kg1) ----
        if (chain == 0) {
            float4 acc[3] = {{0,0,0,0},{0,0,0,0},{0,0,0,0}};
            int a = kg0, b = (kg1 < Ka) ? kg1 : Ka;
            if (a < b) gemm_range<3>(WpC, ld, sA, a, b, acc);
            a = (kg0 > Ka) ? kg0 : Ka; b = kg1;
            if (a < b) gemm_range<3>(UpC, ld, sA, a, b, acc);
            #pragma unroll
            for (int g = 0; g < 3; ++g) {
                sG[grp * 4096 + 0 * 1024 + g * 256 + c] = acc[g].x;
                sG[grp * 4096 + 1 * 1024 + g * 256 + c] = acc[g].y;
                sG[grp * 4096 + 2 * 1024 + g * 256 + c] = acc[g].z;
                sG[grp * 4096 + 3 * 1024 + g * 256 + c] = acc[g].w;
            }
        } else {
            float4 acc[4] = {{0,0,0,0},{0,0,0,0},{0,0,0,0},{0,0,0,0}};
            int a = kg0, b = (kg1 < Ka) ? kg1 : Ka;
            if (a < b) gemm_range<4>(WpC, ld, sA, a, b, acc);
            a = (kg0 > Ka) ? kg0 : Ka; b = kg1;
            if (a < b) gemm_range<4>(UpC, ld, sA, a, b, acc);
            #pragma unroll
            for (int g = 0; g < 4; ++g) {
                sG[grp * 4096 + 0 * 1024 + g * 256 + c] = acc[g].x;
                sG[grp * 4096 + 1 * 1024 + g * 256 + c] = acc[g].y;
                sG[grp * 4096 + 2 * 1024 + g * 256 + c] = acc[g].z;
                sG[grp * 4096 + 3 * 1024 + g * 256 + c] = acc[g].w;
            }
        }
        __syncthreads();

        // ---- L0 anti-clobber: slot t&15 holds h0(t-16), staged by L1 at step t-16
        //      (flag t-15). Slack = 15 rounds >> publish->observe latency.
        if (layer == 0 && t >= NS) {
            if (tid == 0) {
                while (__hip_atomic_load(myflag, __ATOMIC_ACQUIRE,
                                         __HIP_MEMORY_SCOPE_AGENT) < t - NS + 1)
                    __builtin_amdgcn_s_sleep(1);
            }
            __syncthreads();
        }

        // ---- state update: 2 elements/thread (rows rA, rA+2 at column c) ----
        float vh0 = 0.0f, vh1 = 0.0f;
        #pragma unroll
        for (int e = 0; e < 2; ++e) {
            const int r = rA + e * 2;
            const float hold = sA[(Ka + c) * 4 + r];
            const int len = e ? lenB : lenA;
            float hn;
            if (chain == 0) {
                const float Pz = sG[r * 1024 + 0 * 256 + c];
                const float Pr = sG[r * 1024 + 1 * 256 + c];
                const float Ph = sG[r * 1024 + 2 * 256 + c];
                const float Qz = sG[4096 + r * 1024 + 0 * 256 + c];
                const float Qr = sG[4096 + r * 1024 + 1 * 256 + c];
                const float Qh = sG[4096 + r * 1024 + 2 * 256 + c];
                const float z  = sigf(Pz + Qz + bz);
                const float rr = sigf(Pr + Qr + b1);
                const float hh = tanhf(Ph + b2 + rr * (Qh + b3));
                hn = z * hold + (1.0f - z) * hh;
                if (t >= len) hn = hold;
            } else {
                const float gi = sG[r * 1024 + 0 * 256 + c] + sG[4096 + r * 1024 + 0 * 256 + c] + bz;
                const float gf = sG[r * 1024 + 1 * 256 + c] + sG[4096 + r * 1024 + 1 * 256 + c] + b1;
                const float gc = sG[r * 1024 + 2 * 256 + c] + sG[4096 + r * 1024 + 2 * 256 + c] + b2;
                const float go = sG[r * 1024 + 3 * 256 + c] + sG[4096 + r * 1024 + 3 * 256 + c] + b3;
                const float cold = e ? creg1 : creg0;
                float cn = sigf(gf) * cold + sigf(gi) * tanhf(gc);
                hn = sigf(go) * tanhf(cn);
                if (t >= len) { hn = hold; cn = cold; }
                if (e) creg1 = cn; else creg0 = cn;
            }
            sA[(Ka + c) * 4 + r] = hn;   // own h(t) for next step (same-thread slot)
            if (layer == 0) {
                __hip_atomic_exchange(
                    ring + (size_t)(t & (NS - 1)) * RBH + (rowbase + r) * Hh + c,
                    ((unsigned long long)__float_as_uint(hn) << 32) | (unsigned)(t + 1),
                    __ATOMIC_RELAXED, __HIP_MEMORY_SCOPE_AGENT);
            } else {
                if (e) vh1 = hn * ow; else vh0 = hn * ow;
            }
        }

        if (layer == 1) {
            // head: reduce 256 cols per row -> atomicAdd(out)
            const int w = tid >> 6;
            for (int o = 32; o > 0; o >>= 1) {
                vh0 += __shfl_down(vh0, o);
                vh1 += __shfl_down(vh1, o);
            }
            if ((tid & 63) == 0) { sRed[w] = vh0; sRed[8 + w] = vh1; }
            __syncthreads();
            if (tid < 4) {   // rows 0..3: slots {0-3},{4-7},{8-11},{12-15}
                const float s = sRed[tid * 4] + sRed[tid * 4 + 1]
                              + sRed[tid * 4 + 2] + sRed[tid * 4 + 3];
                atomicAdd(&out[(long)(rowbase + tid) * Tt + t],
                          s + (chain ? outb0 : 0.0f));
            }
        }
        __syncthreads();   // own-h writes + sRed visible before next iteration
    }
}

extern "C" void kernel_launch(void* const* d_in, const int* in_sizes, int n_in,
                              void* d_out, int out_size, void* d_ws, size_t ws_size,
                              hipStream_t stream) {
    const float* x       = (const float*)d_in[0];
    const int*   lengths = (const int*)d_in[1];
    const float* gW0  = (const float*)d_in[2];
    const float* gU0  = (const float*)d_in[3];
    const float* gbi0 = (const float*)d_in[4];
    const float* gbr0 = (const float*)d_in[5];
    const float* gW1  = (const float*)d_in[6];
    const float* gU1  = (const float*)d_in[7];
    const float* gbi1 = (const float*)d_in[8];
    const float* gbr1 = (const float*)d_in[9];
    const float* lW0  = (const float*)d_in[10];
    const float* lU0  = (const float*)d_in[11];
    const float* lb0  = (const float*)d_in[12];
    const float* lW1  = (const float*)d_in[13];
    const float* lU1  = (const float*)d_in[14];
    const float* lb1  = (const float*)d_in[15];
    const float* outW = (const float*)d_in[16];
    const float* outb = (const float*)d_in[17];
    float* out = (float*)d_out;
    float* ws  = (float*)d_ws;

    // zero rings (4MB, tag 0 = empty) + flags (4KB)
    hipMemsetAsync(d_ws, 0, (4 << 20) + 4096, stream);
    hipMemsetAsync(d_out, 0, (size_t)out_size * sizeof(float), stream);

    rnn_persist<<<dim3(64), dim3(512), 0, stream>>>(
        x, lengths, gW0, gU0, gbi0, gbr0, gW1, gU1, gbi1, gbr1,
        lW0, lU0, lb0, lW1, lU1, lb1, outW, outb, out, ws);
}

// Round 9
// 6708.057 us; speedup vs baseline: 3.6784x; 1.9997x over previous
//
#include <hip/hip_runtime.h>
#include <hip/hip_fp16.h>

// B=64, T=512, D=96, H=256
constexpr int Tt = 512, Dd = 96, Hh = 256;
constexpr int NS0 = 16;   // h0 ring depth
constexpr int NSP = 8;    // P ring depth
typedef unsigned long long u64;

// ws byte offsets:
//  [0,4MB):  h0 rings: (chain*16+rg) x NS0 slots x 1024 tagged u64
//  [4,12MB): P0 rings: (chain*16+rg) x NSP slots x 4096 tagged u64
//  [12,20MB): P1 rings, same shape
//  [20MB, +16KB): flags (consumed-progress per role), 128B spacing
//  [20MB+64KB, +3MB): fp16-paired weights (converted per launch)
constexpr size_t OFF_P0  = (size_t)4 << 20;
constexpr size_t OFF_P1  = (size_t)12 << 20;
constexpr size_t OFF_FLG = (size_t)20 << 20;
constexpr size_t OFF_W16 = ((size_t)20 << 20) + ((size_t)64 << 10);
// paired-weight offsets in uint units: dst[kp*ld + col] = half2(w[2kp][col], w[2kp+1][col])
constexpr size_t oGW0 = 0;
constexpr size_t oGU0 = oGW0 + (size_t)48 * 768;
constexpr size_t oGW1 = oGU0 + (size_t)128 * 768;
constexpr size_t oGU1 = oGW1 + (size_t)128 * 768;
constexpr size_t oLW0 = oGU1 + (size_t)128 * 768;
constexpr size_t oLU0 = oLW0 + (size_t)48 * 1024;
constexpr size_t oLW1 = oLU0 + (size_t)128 * 1024;
constexpr size_t oLU1 = oLW1 + (size_t)128 * 1024;

__device__ __forceinline__ float sigf(float v) { return 1.0f / (1.0f + __expf(-v)); }
__device__ __forceinline__ u64 agld(const u64* p) {
    return __hip_atomic_load(p, __ATOMIC_RELAXED, __HIP_MEMORY_SCOPE_AGENT);
}
__device__ __forceinline__ int agldi(const int* p) {
    return __hip_atomic_load(p, __ATOMIC_ACQUIRE, __HIP_MEMORY_SCOPE_AGENT);
}

// ---- fp16-pair GEMM: G gate streams x 4 rows, one dword = 2 k's ----
template<int G>
__device__ __forceinline__ void load4(unsigned* wv, const unsigned* __restrict__ M,
                                      int ldm, int kpb) {
    #pragma unroll
    for (int u = 0; u < 4; ++u)
        #pragma unroll
        for (int g = 0; g < G; ++g)
            wv[u * G + g] = M[(size_t)(kpb + u) * ldm + g * Hh];
}
template<int G>
__device__ __forceinline__ void fma4(const unsigned* wv, const float* __restrict__ sA,
                                     int kpb, float4* acc) {
    #pragma unroll
    for (int u = 0; u < 4; ++u) {
        const int kp = kpb + u;
        const float4 a0 = *(const float4*)(sA + (size_t)(2 * kp) * 4);
        const float4 a1 = *(const float4*)(sA + (size_t)(2 * kp + 1) * 4);
        #pragma unroll
        for (int g = 0; g < G; ++g) {
            const __half2 h2 = *(const __half2*)&wv[u * G + g];
            const float2 wf = __half22float2(h2);
            acc[g].x = fmaf(wf.x, a0.x, acc[g].x); acc[g].x = fmaf(wf.y, a1.x, acc[g].x);
            acc[g].y = fmaf(wf.x, a0.y, acc[g].y); acc[g].y = fmaf(wf.y, a1.y, acc[g].y);
            acc[g].z = fmaf(wf.x, a0.z, acc[g].z); acc[g].z = fmaf(wf.y, a1.z, acc[g].z);
            acc[g].w = fmaf(wf.x, a0.w, acc[g].w); acc[g].w = fmaf(wf.y, a1.w, acc[g].w);
        }
    }
}
template<int G>
__device__ __forceinline__ void gemmP(const unsigned* __restrict__ M, int ldm,
                                      const float* __restrict__ sA,
                                      int kp0, int kp1, float4* acc) {
    const int n4 = (kp1 - kp0) >> 2;   // kp ranges are multiples of 4
    unsigned wv0[4 * G], wv1[4 * G];
    if (n4 <= 0) return;
    load4<G>(wv0, M, ldm, kp0);
    int c2 = 0;
    for (; c2 + 2 <= n4; c2 += 2) {
        load4<G>(wv1, M, ldm, kp0 + (c2 + 1) * 4);
        fma4<G>(wv0, sA, kp0 + c2 * 4, acc);
        if (c2 + 2 < n4) load4<G>(wv0, M, ldm, kp0 + (c2 + 2) * 4);
        fma4<G>(wv1, sA, kp0 + (c2 + 1) * 4, acc);
    }
    if (c2 < n4) fma4<G>(wv0, sA, kp0 + c2 * 4, acc);
}

// weight f32 -> paired fp16 (per launch; weights are restored pristine each call)
__global__ void cvt_pair(const float* __restrict__ src, unsigned* __restrict__ dst,
                         int n, int ld) {
    const int i = blockIdx.x * 256 + threadIdx.x;
    if (i >= n) return;
    const int kp = i / ld, col = i - kp * ld;
    const __half2 h = __floats2half2_rn(src[(2 * kp) * ld + col],
                                        src[(2 * kp + 1) * ld + col]);
    dst[i] = *(const unsigned*)&h;
}

// roles: 0 = p0 (x->P0), 1 = r0 (U0 + h0 update), 2 = p1 (h0->P1), 3 = r1 (U1 + head)
// bx = (chain*4+role) + 8*rg  -> XCD class per (chain,role): weight matrix L2-resident
__global__ void __launch_bounds__(512, 1)
rnn_persist(const float* __restrict__ x, const int* __restrict__ lengths,
            const float* __restrict__ gbi0, const float* __restrict__ gbr0,
            const float* __restrict__ gbi1, const float* __restrict__ gbr1,
            const float* __restrict__ lb0, const float* __restrict__ lb1,
            const float* __restrict__ outW, const float* __restrict__ outb,
            float* __restrict__ out, char* __restrict__ wsb)
{
    const int tid = threadIdx.x;
    const int c   = tid & 255;        // owned column
    const int grp = tid >> 8;         // k-split group
    const int bx  = blockIdx.x;
    const int role  = bx & 3;
    const int chain = (bx >> 2) & 1;
    const int rg    = bx >> 3;        // 0..15
    const int rowbase = rg * 4;

    const int GA  = chain ? 4 : 3;
    const int GAH = GA * Hh;          // 768 or 1024 (= ld in elements / uints)

    u64* h0ring = (u64*)wsb + (size_t)(chain * 16 + rg) * (NS0 * 1024);
    u64* p0ring = (u64*)(wsb + OFF_P0) + (size_t)(chain * 16 + rg) * (NSP * 4096);
    u64* p1ring = (u64*)(wsb + OFF_P1) + (size_t)(chain * 16 + rg) * (NSP * 4096);
    int* flags = (int*)(wsb + OFF_FLG);
    int* flg_r0 = flags + ((chain * 16 + rg) * 4 + 1) * 32;
    int* flg_p1 = flags + ((chain * 16 + rg) * 4 + 2) * 32;
    int* flg_r1 = flags + ((chain * 16 + rg) * 4 + 3) * 32;

    const unsigned* W16 = (const unsigned*)(wsb + OFF_W16);
    size_t woff;
    if (chain == 0) woff = (role == 0) ? oGW0 : (role == 1) ? oGU0 : (role == 2) ? oGW1 : oGU1;
    else            woff = (role == 0) ? oLW0 : (role == 1) ? oLU0 : (role == 2) ? oLW1 : oLU1;
    const unsigned* Mc = W16 + woff + c;

    const int KR  = (role == 0) ? Dd : Hh;   // A depth (96 or 256)
    const int KP2 = KR >> 2;                 // kp per group (24 or 64)
    const int kp0 = grp * KP2, kp1 = kp0 + KP2;

    __shared__ __align__(16) float sA[256 * 4];  // A^T[k][4 rows]
    __shared__ float sG[2 * 4096];               // [grp][r*1024 + g*256 + c]
    __shared__ float sP[4096];                   // staged P slot
    __shared__ float sRed[16];

    // per-thread constants
    const int NP  = 4 * GAH;                 // P elements per slot (3072/4096)
    const int npt = NP >> 9;                 // per-thread publish/poll count (6/8)
    float biasv[8];
    int sgidx[8];
    if (role == 0 || role == 2) {
        const float* bsrc = (chain == 0) ? (role == 0 ? gbi0 : gbi1)
                                         : (role == 0 ? lb0 : lb1);
        #pragma unroll
        for (int i = 0; i < 8; ++i) {
            if (i < npt) {
                const int e = tid + i * 512;
                const int r = e / GAH, rem = e - r * GAH;
                biasv[i] = bsrc[rem];
                sgidx[i] = r * 1024 + rem;
            } else { biasv[i] = 0; sgidx[i] = 0; }
        }
    }
    // r-role update constants
    const int rA = tid >> 8;                 // rows rA, rA+2
    const int lenA = lengths[rowbase + rA];
    const int lenB = lengths[rowbase + rA + 2];
    float brz = 0, brr = 0, brh = 0, ow = 0;
    if (chain == 0 && (role == 1 || role == 3)) {
        const float* br = (role == 1) ? gbr0 : gbr1;
        brz = br[c]; brr = br[Hh + c]; brh = br[2 * Hh + c];
    }
    if (role == 3) ow = outW[chain * Hh + c];
    const float outb0 = outb[0];
    float creg0 = 0.0f, creg1 = 0.0f;

    // own-h init (r roles); harmless for p roles
    for (int i = tid; i < 1024; i += 512) sA[i] = 0.0f;
    __syncthreads();

    for (int t = 0; t < Tt; ++t) {
        // =========== PHASE 1: acquire input / anti-clobber ===========
        if (role == 0) {
            if (t >= NSP) {                       // slot t&7 must be consumed by r0
                if (tid == 0)
                    while (agldi(flg_r0) < t - NSP + 1) __builtin_amdgcn_s_sleep(1);
                __syncthreads();
            }
            if (tid < 4 * Dd) {
                const int r = tid / Dd, k = tid - r * Dd;
                sA[k * 4 + r] = x[((size_t)(rowbase + r) * Tt + t) * Dd + k];
            }
            __syncthreads();
        } else if (role == 2) {
            // poll h0(t): 2 tagged elems/thread
            const u64* base = h0ring + (size_t)(t & (NS0 - 1)) * 1024;
            const unsigned want = (unsigned)(t + 1);
            const int r0 = rA, r1 = rA + 2;
            const u64* p0 = base + r0 * 256 + c;
            const u64* p1 = base + r1 * 256 + c;
            u64 v0 = 0, v1 = 0; bool d0 = false, d1 = false;
            do {
                if (!d0) { v0 = agld(p0); d0 = ((unsigned)v0 == want); }
                if (!d1) { v1 = agld(p1); d1 = ((unsigned)v1 == want); }
            } while (!(d0 && d1));
            sA[c * 4 + r0] = __uint_as_float((unsigned)(v0 >> 32));
            sA[c * 4 + r1] = __uint_as_float((unsigned)(v1 >> 32));
            __syncthreads();
            if (tid == 0)
                __hip_atomic_exchange(flg_p1, t + 1, __ATOMIC_RELEASE,
                                      __HIP_MEMORY_SCOPE_AGENT);
        } else {
            // r0 / r1: poll the P slot into sP
            u64* ring = (role == 1) ? p0ring : p1ring;
            const u64* slot = ring + (size_t)(t & (NSP - 1)) * 4096;
            const unsigned want = (unsigned)(t + 1);
            unsigned dm = 0;
            const unsigned full = (1u << npt) - 1u;
            while (dm != full) {
                for (int i = 0; i < npt; ++i) {
                    if (!(dm & (1u << i))) {
                        const u64 v = agld(slot + tid + i * 512);
                        if ((unsigned)v == want) {
                            sP[tid + i * 512] = __uint_as_float((unsigned)(v >> 32));
                            dm |= 1u << i;
                        }
                    }
                }
            }
            __syncthreads();
            if (tid == 0)
                __hip_atomic_exchange((role == 1) ? flg_r0 : flg_r1, t + 1,
                                      __ATOMIC_RELEASE, __HIP_MEMORY_SCOPE_AGENT);
        }

        // =========== PHASE 2: GEMM (fp16 weights, A broadcast from LDS) ===========
        {
            if (chain == 0) {
                float4 acc[3] = {{0,0,0,0},{0,0,0,0},{0,0,0,0}};
                gemmP<3>(Mc, GAH, sA, kp0, kp1, acc);
                #pragma unroll
                for (int g = 0; g < 3; ++g) {
                    sG[grp * 4096 + 0 * 1024 + g * 256 + c] = acc[g].x;
                    sG[grp * 4096 + 1 * 1024 + g * 256 + c] = acc[g].y;
                    sG[grp * 4096 + 2 * 1024 + g * 256 + c] = acc[g].z;
                    sG[grp * 4096 + 3 * 1024 + g * 256 + c] = acc[g].w;
                }
            } else {
                float4 acc[4] = {{0,0,0,0},{0,0,0,0},{0,0,0,0},{0,0,0,0}};
                gemmP<4>(Mc, GAH, sA, kp0, kp1, acc);
                #pragma unroll
                for (int g = 0; g < 4; ++g) {
                    sG[grp * 4096 + 0 * 1024 + g * 256 + c] = acc[g].x;
                    sG[grp * 4096 + 1 * 1024 + g * 256 + c] = acc[g].y;
                    sG[grp * 4096 + 2 * 1024 + g * 256 + c] = acc[g].z;
                    sG[grp * 4096 + 3 * 1024 + g * 256 + c] = acc[g].w;
                }
            }
        }
        __syncthreads();

        // =========== PHASE 3: publish (p roles) / update (r roles) ===========
        if (role == 0 || role == 2) {
            // anti-clobber for the P slot we're about to overwrite
            if (role == 2 && t >= NSP) {
                if (tid == 0)
                    while (agldi(flg_r1) < t - NSP + 1) __builtin_amdgcn_s_sleep(1);
                __syncthreads();
            }
            u64* ring = (role == 0) ? p0ring : p1ring;
            u64* slot = ring + (size_t)(t & (NSP - 1)) * 4096;
            for (int i = 0; i < npt; ++i) {
                const int e = tid + i * 512;
                const float v = sG[sgidx[i]] + sG[4096 + sgidx[i]] + biasv[i];
                atomicExch(slot + e,
                           ((u64)__float_as_uint(v) << 32) | (unsigned)(t + 1));
            }
        } else {
            // r0: anti-clobber h0 ring slot (p1 must have consumed h0(t-16))
            if (role == 1 && t >= NS0) {
                if (tid == 0)
                    while (agldi(flg_p1) < t - NS0 + 1) __builtin_amdgcn_s_sleep(1);
                __syncthreads();
            }
            float vh0 = 0.0f, vh1 = 0.0f;
            #pragma unroll
            for (int e = 0; e < 2; ++e) {
                const int r = rA + e * 2;
                const float hold = sA[c * 4 + r];
                const int len = e ? lenB : lenA;
                float hn;
                if (chain == 0) {
                    const float Pz = sP[r * GAH + c];
                    const float Pr = sP[r * GAH + Hh + c];
                    const float Ph = sP[r * GAH + 2 * Hh + c];
                    const float Qz = sG[r * 1024 + c]       + sG[4096 + r * 1024 + c];
                    const float Qr = sG[r * 1024 + 256 + c] + sG[4096 + r * 1024 + 256 + c];
                    const float Qh = sG[r * 1024 + 512 + c] + sG[4096 + r * 1024 + 512 + c];
                    const float z  = sigf(Pz + Qz + brz);
                    const float rr = sigf(Pr + Qr + brr);
                    const float hh = tanhf(Ph + rr * (Qh + brh));
                    hn = z * hold + (1.0f - z) * hh;
                    if (t >= len) hn = hold;
                } else {
                    const float gi = sP[r * GAH + c]          + sG[r * 1024 + c]       + sG[4096 + r * 1024 + c];
                    const float gf = sP[r * GAH + Hh + c]     + sG[r * 1024 + 256 + c] + sG[4096 + r * 1024 + 256 + c];
                    const float gc = sP[r * GAH + 2 * Hh + c] + sG[r * 1024 + 512 + c] + sG[4096 + r * 1024 + 512 + c];
                    const float go = sP[r * GAH + 3 * Hh + c] + sG[r * 1024 + 768 + c] + sG[4096 + r * 1024 + 768 + c];
                    const float cold = e ? creg1 : creg0;
                    float cn = sigf(gf) * cold + sigf(gi) * tanhf(gc);
                    hn = sigf(go) * tanhf(cn);
                    if (t >= len) { hn = hold; cn = cold; }
                    if (e) creg1 = cn; else creg0 = cn;
                }
                sA[c * 4 + r] = hn;                       // own h(t)
                if (role == 1) {
                    __hip_atomic_exchange(
                        h0ring + (size_t)(t & (NS0 - 1)) * 1024 + r * 256 + c,
                        ((u64)__float_as_uint(hn) << 32) | (unsigned)(t + 1),
                        __ATOMIC_RELAXED, __HIP_MEMORY_SCOPE_AGENT);
                } else {
                    if (e) vh1 = hn * ow; else vh0 = hn * ow;
                }
            }
            if (role == 3) {
                const int w = tid >> 6;
                for (int o = 32; o > 0; o >>= 1) {
                    vh0 += __shfl_down(vh0, o);
                    vh1 += __shfl_down(vh1, o);
                }
                if ((tid & 63) == 0) { sRed[w] = vh0; sRed[8 + w] = vh1; }
                __syncthreads();
                if (tid < 4) {
                    const float s = sRed[tid * 4] + sRed[tid * 4 + 1]
                                  + sRed[tid * 4 + 2] + sRed[tid * 4 + 3];
                    atomicAdd(&out[(size_t)(rowbase + tid) * Tt + t],
                              s + (chain ? outb0 : 0.0f));
                }
            }
        }
        __syncthreads();   // sP/sG/sRed safe for next iteration
    }
}

extern "C" void kernel_launch(void* const* d_in, const int* in_sizes, int n_in,
                              void* d_out, int out_size, void* d_ws, size_t ws_size,
                              hipStream_t stream) {
    const float* x       = (const float*)d_in[0];
    const int*   lengths = (const int*)d_in[1];
    const float* gW0  = (const float*)d_in[2];
    const float* gU0  = (const float*)d_in[3];
    const float* gbi0 = (const float*)d_in[4];
    const float* gbr0 = (const float*)d_in[5];
    const float* gW1  = (const float*)d_in[6];
    const float* gU1  = (const float*)d_in[7];
    const float* gbi1 = (const float*)d_in[8];
    const float* gbr1 = (const float*)d_in[9];
    const float* lW0  = (const float*)d_in[10];
    const float* lU0  = (const float*)d_in[11];
    const float* lb0  = (const float*)d_in[12];
    const float* lW1  = (const float*)d_in[13];
    const float* lU1  = (const float*)d_in[14];
    const float* lb1  = (const float*)d_in[15];
    const float* outW = (const float*)d_in[16];
    const float* outb = (const float*)d_in[17];
    float* out = (float*)d_out;
    char* wsb  = (char*)d_ws;

    // zero rings + flags (tags must start 0)
    hipMemsetAsync(d_ws, 0, OFF_FLG + (16 << 10), stream);
    hipMemsetAsync(d_out, 0, (size_t)out_size * sizeof(float), stream);

    // convert weights to paired fp16 (re-done every call; inputs pristine)
    unsigned* W16 = (unsigned*)(wsb + OFF_W16);
    struct { const float* s; size_t o; int K; int ld; } cv[8] = {
        {gW0, oGW0, 96, 768}, {gU0, oGU0, 256, 768},
        {gW1, oGW1, 256, 768}, {gU1, oGU1, 256, 768},
        {lW0, oLW0, 96, 1024}, {lU0, oLU0, 256, 1024},
        {lW1, oLW1, 256, 1024}, {lU1, oLU1, 256, 1024},
    };
    for (int i = 0; i < 8; ++i) {
        const int n = (cv[i].K / 2) * cv[i].ld;
        cvt_pair<<<(n + 255) / 256, 256, 0, stream>>>(cv[i].s, W16 + cv[i].o, n, cv[i].ld);
    }

    rnn_persist<<<dim3(128), dim3(512), 0, stream>>>(
        x, lengths, gbi0, gbr0, gbi1, gbr1, lb0, lb1, outW, outb, out, wsb);
}